// Round 10
// baseline (214.053 us; speedup 1.0000x reference)
//
#include <hip/hip_runtime.h>

#define F 128
#define TILE 16
#define NTHR 256

typedef __attribute__((ext_vector_type(8))) __bf16 bf16x8;
typedef __attribute__((ext_vector_type(4))) float f32x4;
typedef __attribute__((ext_vector_type(8))) unsigned short us8;
typedef __attribute__((ext_vector_type(4))) unsigned short us4;
typedef __attribute__((ext_vector_type(2))) unsigned short us2;
typedef unsigned short us;

struct f3 { float x, y, z; };   // 12B -> global_store_dwordx3

#define MFMA(a,b,c) __builtin_amdgcn_mfma_f32_16x16x32_bf16((a),(b),(c),0,0,0)

__device__ __forceinline__ us f2bf(float x) {
    __bf16 h = (__bf16)x;                       // HW v_cvt (RNE)
    return __builtin_bit_cast(us, h);
}
__device__ __forceinline__ float bf2f(us u) {
    unsigned x = ((unsigned)u) << 16;
    return __builtin_bit_cast(float, x);
}
__device__ __forceinline__ bf16x8 pack8(float4 a, float4 b) {
    us8 t;
    t[0] = f2bf(a.x); t[1] = f2bf(a.y); t[2] = f2bf(a.z); t[3] = f2bf(a.w);
    t[4] = f2bf(b.x); t[5] = f2bf(b.y); t[6] = f2bf(b.z); t[7] = f2bf(b.w);
    return __builtin_bit_cast(bf16x8, t);
}
__device__ __forceinline__ void gload16(const float* g, const us* l) {
    __builtin_amdgcn_global_load_lds(
        (const __attribute__((address_space(1))) void*)g,
        (__attribute__((address_space(3))) void*)l, 16, 0, 0);
}
__device__ __forceinline__ void bar_lgkm() {
    asm volatile("s_waitcnt lgkmcnt(0)" ::: "memory");
    __builtin_amdgcn_s_barrier();
}

// LDS map (ushort units), 18432 sh = 36864 B -> 4 blocks/CU (147456 <= 163840)
//  RAWV [0,12288)   : raw f32 v tile (16x128x3), linear (dead after convert)
//  A2   [0,4224)    : OVERLAY on raw after convert: 16 x 264 (s bf16 | nrm bf16)
//  A3   [4224,6400) : OVERLAY: 16 x 136 (h bf16)
//  VR   [12288,18432): v bf16, 48 rows (crow=c*16+nl) x 128, XOR-swizzled
#define RAWV 0
#define A2B  0
#define A2S  264
#define A3B  4224
#define A3S  136
#define VRB  12288
#define SHSZ 18432

__device__ __forceinline__ int vr_idx(int crow, int k) {
    return VRB + (((crow << 7) + k) ^ ((crow & 7) << 3));
}

__global__ __launch_bounds__(256)
void prep_w(const float* __restrict__ Uw, const float* __restrict__ Vw,
            const float* __restrict__ aw1, const float* __restrict__ aw2,
            us* __restrict__ wbf)
{
    int i = (blockIdx.x * 256 + threadIdx.x) * 4;   // 112x256x4 = 114688
    const float* src; int off;
    if (i < 16384)      { src = Uw;  off = i; }
    else if (i < 32768) { src = Vw;  off = i - 16384; }
    else if (i < 65536) { src = aw1; off = i - 32768; }
    else                { src = aw2; off = i - 65536; }
    float4 x = *(const float4*)&src[off];
    us4 o;
    o[0] = f2bf(x.x); o[1] = f2bf(x.y); o[2] = f2bf(x.z); o[3] = f2bf(x.w);
    *(us4*)&wbf[i] = o;
}

template<bool PRE>
__global__ __launch_bounds__(NTHR) __attribute__((amdgpu_waves_per_eu(4)))
void painn_one(const float* __restrict__ s, const float* __restrict__ v,
               const float* __restrict__ Uw, const float* __restrict__ Vw,
               const float* __restrict__ aw1, const float* __restrict__ ab1,
               const float* __restrict__ aw2, const float* __restrict__ ab2,
               const us* __restrict__ wbf,
               float* __restrict__ out, int Ntot)
{
    __shared__ __align__(16) us SH[SHSZ];

    const int tid  = threadIdx.x;
    const int lane = tid & 63;
    const int w    = tid >> 6;        // wave 0..3
    const int l15  = lane & 15;
    const int kp   = lane >> 4;       // 0..3
    const int t    = blockIdx.x;      // one 16-row tile per block
    const size_t NF = (size_t)Ntot * F;

    const us* wU  = wbf;
    const us* wV  = wbf + 16384;
    const us* wW1 = wbf + 32768;
    const us* wW2 = wbf + 65536;

    const int srow = tid >> 4;           // s row 0..15
    const int sf0  = (tid & 15) << 3;    // s f-offset (8 floats)

    const float* rawv = (const float*)&SH[RAWV];

    // ---- prologue: async v tile -> raw LDS; s -> regs ----
    {
        const float* vsrc = v + (size_t)t * TILE * 384;
        #pragma unroll
        for (int j = 0; j < 6; ++j) {
            int ofs = (w + j * 4) * 256;               // floats; 1KB per wave-round
            gload16(vsrc + ofs + lane * 4, &SH[RAWV + ofs * 2]);
        }
    }
    float4 sp0, sp1;
    {
        const float* ssrc = s + (size_t)t * TILE * 128 + srow * 128 + sf0;
        sp0 = *(const float4*)ssrc;
        sp1 = *(const float4*)(ssrc + 4);
    }
    asm volatile("s_waitcnt vmcnt(0)" ::: "memory");
    __builtin_amdgcn_s_barrier();                     // B0: raw + s regs ready

    // ---- convert v: raw f32 -> VR (bf16, c-major rows, swizzled) ----
    #pragma unroll
    for (int it = 0; it < 4; ++it) {
        int idx = tid + it * 256;          // 1024 tasks: 16 rows x 64 f-pairs
        int nl  = idx >> 6;
        int f0  = (idx & 63) << 1;
        const float2* src = (const float2*)&rawv[nl * 384 + f0 * 3];
        float2 ab = src[0], cd = src[1], ef = src[2];
        us2 p;
        p[0] = f2bf(ab.x); p[1] = f2bf(cd.y); *(us2*)&SH[vr_idx(0 * TILE + nl, f0)] = p;
        p[0] = f2bf(ab.y); p[1] = f2bf(ef.x); *(us2*)&SH[vr_idx(1 * TILE + nl, f0)] = p;
        p[0] = f2bf(cd.x); p[1] = f2bf(ef.y); *(us2*)&SH[vr_idx(2 * TILE + nl, f0)] = p;
    }
    bar_lgkm();                                       // B1: VR ready, raw dead

    // ---- A2 s-half (overlay on dead raw region) ----
    {
        us4 t0, t1;
        t0[0] = f2bf(sp0.x); t0[1] = f2bf(sp0.y); t0[2] = f2bf(sp0.z); t0[3] = f2bf(sp0.w);
        t1[0] = f2bf(sp1.x); t1[1] = f2bf(sp1.y); t1[2] = f2bf(sp1.z); t1[3] = f2bf(sp1.w);
        *(us4*)&SH[A2B + srow * A2S + sf0]     = t0;
        *(us4*)&SH[A2B + srow * A2S + sf0 + 4] = t1;
    }

    // ---- stage 1: Uv, Vv — two column passes; nrm -> A2; keep pU, inr ----
    float inr[2][4];
    us4 pU[2][3];
    #pragma unroll
    for (int p = 0; p < 2; ++p) {
        const int colp = p * 64 + (w << 4) + l15;
        bf16x8 bU[4], bV[4];
        #pragma unroll
        for (int ks = 0; ks < 4; ++ks) {
            int k0 = (ks << 5) + (kp << 3);
            if constexpr (PRE) {
                bU[ks] = *(const bf16x8*)&wU[colp * F + k0];
                bV[ks] = *(const bf16x8*)&wV[colp * F + k0];
            } else {
                const float4* pu = (const float4*)&Uw[colp * F + k0];
                bU[ks] = pack8(pu[0], pu[1]);
                const float4* pv = (const float4*)&Vw[colp * F + k0];
                bV[ks] = pack8(pv[0], pv[1]);
            }
        }
        float nrm[4];
        #pragma unroll
        for (int c = 0; c < 3; ++c) {
            f32x4 aU = (f32x4){0.f,0.f,0.f,0.f};
            f32x4 aV = (f32x4){0.f,0.f,0.f,0.f};
            #pragma unroll
            for (int ks = 0; ks < 4; ++ks) {
                bf16x8 a = *(const bf16x8*)&SH[vr_idx(c * TILE + l15, (ks << 5) + (kp << 3))];
                aU = MFMA(a, bU[ks], aU);
                aV = MFMA(a, bV[ks], aV);
            }
            us4 q;
            #pragma unroll
            for (int r = 0; r < 4; ++r) {
                float uu = aU[r], vv = aV[r];
                if (c == 0) { nrm[r] = vv * vv; inr[p][r] = uu * vv; }
                else        { nrm[r] += vv * vv; inr[p][r] += uu * vv; }
                q[r] = f2bf(uu);
            }
            pU[p][c] = q;
        }
        #pragma unroll
        for (int r = 0; r < 4; ++r) {
            int row = (kp << 2) + r;
            SH[A2B + row * A2S + 128 + colp] = f2bf(nrm[r]);
        }
    }
    bar_lgkm();                                       // B2: A2 complete

    // ---- stage 2: h = shifted_softplus(mlp_in @ w1.T + b1), two passes ----
    #pragma unroll
    for (int p = 0; p < 2; ++p) {
        const int colp = p * 64 + (w << 4) + l15;
        f32x4 accH = (f32x4){0.f,0.f,0.f,0.f};
        #pragma unroll
        for (int ks = 0; ks < 8; ++ks) {
            int k0 = (ks << 5) + (kp << 3);
            bf16x8 bw;
            if constexpr (PRE) {
                bw = *(const bf16x8*)&wW1[colp * 256 + k0];
            } else {
                const float4* pp = (const float4*)&aw1[colp * 256 + k0];
                bw = pack8(pp[0], pp[1]);
            }
            bf16x8 a = *(const bf16x8*)&SH[A2B + l15 * A2S + k0];
            accH = MFMA(a, bw, accH);
        }
        float b1 = ab1[colp];
        #pragma unroll
        for (int r = 0; r < 4; ++r) {
            float x = accH[r] + b1;
            float hsp = fmaxf(x, 0.f) + __logf(1.f + __expf(-fabsf(x))) - 0.69314718056f;
            int row = (kp << 2) + r;
            SH[A3B + row * A3S + colp] = f2bf(hsp);
        }
    }
    bar_lgkm();                                       // B3: A3 ready

    // ---- stage 3 + epilogue, two passes ----
    #pragma unroll
    for (int p = 0; p < 2; ++p) {
        const int colp = p * 64 + (w << 4) + l15;
        bf16x8 bWs[4], bWt[4], bWv[4];
        #pragma unroll
        for (int ks = 0; ks < 4; ++ks) {
            int k0 = (ks << 5) + (kp << 3);
            if constexpr (PRE) {
                bWs[ks] = *(const bf16x8*)&wW2[(0 * F + colp) * F + k0];
                bWt[ks] = *(const bf16x8*)&wW2[(1 * F + colp) * F + k0];
                bWv[ks] = *(const bf16x8*)&wW2[(2 * F + colp) * F + k0];
            } else {
                const float4* p0 = (const float4*)&aw2[(size_t)(0 * F + colp) * F + k0];
                const float4* p1 = (const float4*)&aw2[(size_t)(1 * F + colp) * F + k0];
                const float4* p2 = (const float4*)&aw2[(size_t)(2 * F + colp) * F + k0];
                bWs[ks] = pack8(p0[0], p0[1]);
                bWt[ks] = pack8(p1[0], p1[1]);
                bWv[ks] = pack8(p2[0], p2[1]);
            }
        }
        f32x4 accS = (f32x4){0.f,0.f,0.f,0.f};
        f32x4 accT = (f32x4){0.f,0.f,0.f,0.f};
        f32x4 accA = (f32x4){0.f,0.f,0.f,0.f};
        #pragma unroll
        for (int ks = 0; ks < 4; ++ks) {
            int k0 = (ks << 5) + (kp << 3);
            bf16x8 a = *(const bf16x8*)&SH[A3B + l15 * A3S + k0];
            accS = MFMA(a, bWs[ks], accS);
            accT = MFMA(a, bWt[ks], accT);
            accA = MFMA(a, bWv[ks], accA);
        }
        float bss = ab2[colp];
        float bsv = ab2[F + colp];
        float bvv = ab2[2 * F + colp];
        #pragma unroll
        for (int r = 0; r < 4; ++r) {
            int nl = (kp << 2) + r;
            size_t n = (size_t)t * TILE + nl;
            // s_new
            float sres = bf2f(SH[A2B + nl * A2S + colp]);
            out[n * 128 + colp] = sres + (accS[r] + bss) + (accT[r] + bsv) * inr[p][r];
            // v_new (residual from VR bf16, as validated since R2)
            float avv = accA[r] + bvv;
            f3 val;
            val.x = bf2f(SH[vr_idx(0 * TILE + nl, colp)]) + avv * bf2f(pU[p][0][r]);
            val.y = bf2f(SH[vr_idx(1 * TILE + nl, colp)]) + avv * bf2f(pU[p][1][r]);
            val.z = bf2f(SH[vr_idx(2 * TILE + nl, colp)]) + avv * bf2f(pU[p][2][r]);
            *(f3*)&out[NF + (n * 128 + colp) * 3] = val;
        }
    }
}

extern "C" void kernel_launch(void* const* d_in, const int* in_sizes, int n_in,
                              void* d_out, int out_size, void* d_ws, size_t ws_size,
                              hipStream_t stream) {
    (void)n_in; (void)out_size;
    const float* s   = (const float*)d_in[0];
    const float* v   = (const float*)d_in[1];
    const float* Uw  = (const float*)d_in[2];
    const float* Vw  = (const float*)d_in[3];
    const float* aw1 = (const float*)d_in[4];
    const float* ab1 = (const float*)d_in[5];
    const float* aw2 = (const float*)d_in[6];
    const float* ab2 = (const float*)d_in[7];
    float* out = (float*)d_out;
    int Ntot = in_sizes[0] / F;                 // 100000 (divisible by TILE=16)
    int NT   = Ntot / TILE;                     // 6250

    if (ws_size >= 114688ull * sizeof(us)) {
        us* wbf = (us*)d_ws;
        hipLaunchKernelGGL(prep_w, dim3(112), dim3(256), 0, stream, Uw, Vw, aw1, aw2, wbf);
        hipLaunchKernelGGL((painn_one<true>), dim3(NT), dim3(NTHR), 0, stream,
                           s, v, Uw, Vw, aw1, ab1, aw2, ab2, wbf, out, Ntot);
    } else {
        hipLaunchKernelGGL((painn_one<false>), dim3(NT), dim3(NTHR), 0, stream,
                           s, v, Uw, Vw, aw1, ab1, aw2, ab2, (const us*)nullptr, out, Ntot);
    }
}